// Round 6
// baseline (134.944 us; speedup 1.0000x reference)
//
#include <hip/hip_runtime.h>
#include <hip/hip_bf16.h>

// ControlFieldModule (fp32 I/O). Barrier-free MFMA-bf16 GEMM, zero LDS.
//   fiber = H @ Wf + bf; h = gelu([H|fiber]@W1+b1); delta = clip(softplus(h@w2+b2),0,1)
//   field = EMA(delta,0.9) clip[0,10]; gate = sigmoid(-field)
// One GEMM C[32768,96] = H @ [Wf | W1h + Wf@W1f] (bias folded into bc).
// A: each wave owns 16 tokens x K=512 in registers (2 half-bursts of dwordx4).
// B: 96 KB bf16, L1/L2-resident, fragments loaded DIRECTLY from global in
// MFMA B-layout (16-B contiguous per lane) interleaved 1:1 with MFMA.
// No __syncthreads in the GEMM at all. EMA: 256-tap causal FIR (128 blocks).

#define NTOK  32768   // 8 * 4096
#define SEQ   4096
#define DM    512
#define NC    96      // 32 fiber + 64 control cols
#define TB    64      // tokens per block

typedef short bf16x8 __attribute__((ext_vector_type(8)));
typedef float f32x4  __attribute__((ext_vector_type(4)));

__device__ __forceinline__ unsigned short f2bf(float f) {
    __hip_bfloat16 h = __float2bfloat16(f);
    return *reinterpret_cast<unsigned short*>(&h);
}

// ---- kernel 1: Wt = [Wf | W1h + Wf@W1f]^T bf16 [96][512]; bc fp32 [96] ----
__global__ __launch_bounds__(256)
void prep_kernel(const float* __restrict__ wf,   // [512,32]
                 const float* __restrict__ bfb,  // [32]
                 const float* __restrict__ w1,   // [544,64]
                 const float* __restrict__ b1,   // [64]
                 unsigned short* __restrict__ Wt, // [96,512] bf16
                 float* __restrict__ bc)          // [96]
{
    int idx = blockIdx.x * 256 + threadIdx.x;     // 0 .. 96*512-1
    if (idx < NC * DM) {
        int n = idx >> 9, k = idx & 511;
        float v;
        if (n < 32) {
            v = wf[k * 32 + n];
        } else {
            int c = n - 32;
            v = w1[k * 64 + c];
            for (int f = 0; f < 32; ++f)
                v = fmaf(wf[k * 32 + f], w1[(512 + f) * 64 + c], v);
        }
        Wt[idx] = f2bf(v);
    }
    if (idx < NC) {
        float v;
        if (idx < 32) {
            v = bfb[idx];
        } else {
            int c = idx - 32;
            v = b1[c];
            for (int f = 0; f < 32; ++f)
                v = fmaf(bfb[f], w1[(512 + f) * 64 + c], v);
        }
        bc[idx] = v;
    }
}

// ---- kernel 2: barrier-free MFMA GEMM, M=64/block, N=96, K=512 ------------
// 256 threads = 4 waves; wave w owns tokens [tok0+16w, tok0+16w+16).
__global__ __launch_bounds__(256)
void fused_gemm_kernel(const float* __restrict__ hidden,        // [NTOK,512]
                       const unsigned short* __restrict__ Wt,   // [96,512] bf16
                       const float* __restrict__ bc,            // [96]
                       const float* __restrict__ w2,            // [64]
                       const float* __restrict__ b2,            // [1]
                       float* __restrict__ out_delta,           // [NTOK]
                       float* __restrict__ out_fiber)           // [NTOK,32]
{
    const int tid  = threadIdx.x;
    const int wave = tid >> 6;
    const int lane = tid & 63;
    const int quad = lane >> 4;
    const int l15  = lane & 15;
    const int tok0 = blockIdx.x * TB;

    // A: this lane's row, fragment ks covers k = ks*32 + quad*8 (8 floats)
    const float* aptr = hidden + (size_t)(tok0 + wave * 16 + l15) * DM + quad * 8;
    // B: fragment (tile t, ks) for this lane = Wt[t*16+l15][ks*32+quad*8], 16 B
    const unsigned short* wbase = Wt + l15 * DM + quad * 8;

    f32x4 acc[6];
#pragma unroll
    for (int t = 0; t < 6; ++t) acc[t] = (f32x4){0.f, 0.f, 0.f, 0.f};

#pragma unroll
    for (int half = 0; half < 2; ++half) {
        // burst: 16 independent dwordx4 for this K-half (8 frags x 32 floats... 8x64B)
        float4 raw[16];
#pragma unroll
        for (int i = 0; i < 16; ++i)            // i = j*2 + part
            raw[i] = *(const float4*)(aptr + half * 256 + (i >> 1) * 32 + (i & 1) * 4);

#pragma unroll
        for (int j = 0; j < 8; ++j) {
            float4 lo = raw[j * 2], hi = raw[j * 2 + 1];
            bf16x8 af;
            af[0] = (short)f2bf(lo.x); af[1] = (short)f2bf(lo.y);
            af[2] = (short)f2bf(lo.z); af[3] = (short)f2bf(lo.w);
            af[4] = (short)f2bf(hi.x); af[5] = (short)f2bf(hi.y);
            af[6] = (short)f2bf(hi.z); af[7] = (short)f2bf(hi.w);
            const int ks = half * 8 + j;
#pragma unroll
            for (int t = 0; t < 6; ++t) {
                bf16x8 bv = *(const bf16x8*)(wbase + t * 16 * DM + ks * 32);
                acc[t] = __builtin_amdgcn_mfma_f32_16x16x32_bf16(af, bv, acc[t], 0, 0, 0);
            }
        }
    }

    // ---- epilogue: C/D layout col=lane&15, row=quad*4+reg ----
    const int mbase = tok0 + wave * 16 + quad * 4;

#pragma unroll
    for (int t = 0; t < 2; ++t) {               // fiber tiles
        int col = t * 16 + l15;
        float bias = bc[col];
#pragma unroll
        for (int r = 0; r < 4; ++r)
            out_fiber[(size_t)(mbase + r) * 32 + col] = acc[t][r] + bias;
    }

    float p0 = 0.f, p1 = 0.f, p2 = 0.f, p3 = 0.f;
#pragma unroll
    for (int t = 2; t < 6; ++t) {               // control tiles: gelu * w2
        int c = (t - 2) * 16 + l15;
        float bias = bc[32 + c];
        float w2v  = w2[c];
        float x, g;
        x = acc[t][0] + bias; g = 0.5f * x * (1.f + erff(x * 0.70710678118f)); p0 = fmaf(g, w2v, p0);
        x = acc[t][1] + bias; g = 0.5f * x * (1.f + erff(x * 0.70710678118f)); p1 = fmaf(g, w2v, p1);
        x = acc[t][2] + bias; g = 0.5f * x * (1.f + erff(x * 0.70710678118f)); p2 = fmaf(g, w2v, p2);
        x = acc[t][3] + bias; g = 0.5f * x * (1.f + erff(x * 0.70710678118f)); p3 = fmaf(g, w2v, p3);
    }
#pragma unroll
    for (int m = 1; m <= 8; m <<= 1) {          // reduce the 16 cols of this quad
        p0 += __shfl_xor(p0, m);
        p1 += __shfl_xor(p1, m);
        p2 += __shfl_xor(p2, m);
        p3 += __shfl_xor(p3, m);
    }
    if (l15 < 4) {
        float pv = (l15 == 0) ? p0 : (l15 == 1) ? p1 : (l15 == 2) ? p2 : p3;
        float s = pv + b2[0];
        float d = (s > 0.f) ? s + log1pf(expf(-s)) : log1pf(expf(s));
        d = fminf(fmaxf(d, 0.f), 1.f);
        out_delta[mbase + l15] = d;
    }
}

// ---- kernel 3: EMA as 256-tap causal FIR + gate (128 blocks) --------------
__global__ __launch_bounds__(256)
void scan_kernel(const float* __restrict__ delta,   // [8,4096]
                 const float* __restrict__ lam,     // scalar
                 float* __restrict__ out_gate,      // [NTOK]
                 float* __restrict__ out_field)     // [NTOK]
{
    __shared__ float lds_d[512];
    const int b     = blockIdx.x >> 4;   // batch row
    const int chunk = blockIdx.x & 15;   // 256-token chunk
    const int s0    = chunk * 256;
    const int tid   = threadIdx.x;

    for (int v = tid; v < 512; v += 256) {
        int s = s0 - 256 + v;
        lds_d[v] = (s >= 0) ? delta[b * SEQ + s] : 0.f;
    }
    __syncthreads();

    float w = 0.1f, acc = 0.f;
    const int base = 256 + tid;
    for (int j = 0; j < 256; ++j) {
        acc = fmaf(w, lds_d[base - j], acc);
        w *= 0.9f;
    }
    float field = fminf(fmaxf(acc, 0.f), 10.f);

    float gate = 1.f / (1.f + expf(lam[0] * field));
    int t = b * SEQ + s0 + tid;
    out_field[t] = field;
    out_gate[t]  = gate;
}

// ---- launcher ----
extern "C" void kernel_launch(void* const* d_in, const int* in_sizes, int n_in,
                              void* d_out, int out_size, void* d_ws, size_t ws_size,
                              hipStream_t stream)
{
    const float* hidden = (const float*)d_in[0];
    const float* wf     = (const float*)d_in[1];
    const float* bfb    = (const float*)d_in[2];
    const float* w1     = (const float*)d_in[3];
    const float* b1     = (const float*)d_in[4];
    const float* w2     = (const float*)d_in[5];
    const float* b2     = (const float*)d_in[6];
    const float* lam    = (const float*)d_in[7];
    float* out = (float*)d_out;
    // out layout: gate[32768] | field[32768] | delta[32768] | fiber[32768*32]
    float* out_gate  = out;
    float* out_field = out + NTOK;
    float* out_delta = out + 2 * NTOK;
    float* out_fiber = out + 3 * NTOK;

    unsigned short* Wt = (unsigned short*)d_ws;                 // 96*512*2 B
    float* bc          = (float*)((char*)d_ws + NC * DM * 2);   // 384 B

    hipLaunchKernelGGL(prep_kernel, dim3((NC * DM + 255) / 256), dim3(256), 0, stream,
                       wf, bfb, w1, b1, Wt, bc);
    hipLaunchKernelGGL(fused_gemm_kernel, dim3(NTOK / TB), dim3(256), 0, stream,
                       hidden, Wt, bc, w2, b2, out_delta, out_fiber);
    hipLaunchKernelGGL(scan_kernel, dim3(128), dim3(256), 0, stream,
                       out_delta, lam, out_gate, out_field);
}